// Round 15
// baseline (661.633 us; speedup 1.0000x reference)
//
#include <hip/hip_runtime.h>
#include <hip/hip_fp16.h>

#define BB 32
#define NI 2048
#define NK 64
#define ND 32
#define KD 2048       // caps_n * caps_dim
#define NL 16
#define ICH 8         // i's per conv block
#define NPC (NI/ICH)  // 256 conv i-chunks (round-0 partial count)
#define NRC 32        // route chunks (64 i each)
#define EPSF 1e-7f

typedef _Float16 f16;
typedef _Float16 h2 __attribute__((ext_vector_type(2)));
typedef __attribute__((ext_vector_type(4))) float f32x4;
typedef __attribute__((ext_vector_type(8))) _Float16 f16x8;
typedef __attribute__((ext_vector_type(16))) float f32x16;
union U4H8 { uint4 u4; h2 h[4]; };

static __device__ __forceinline__ float dot2f(h2 a, h2 b, float c) {
#if __has_builtin(__builtin_amdgcn_fdot2)
  return __builtin_amdgcn_fdot2(a, b, c, false);
#else
  return c + (float)a[0] * (float)b[0] + (float)a[1] * (float)b[1];
#endif
}

static __device__ __forceinline__ float fastrcp(float s) {
#if __has_builtin(__builtin_amdgcn_rcpf)
  return __builtin_amdgcn_rcpf(s);
#else
  return 1.0f / s;
#endif
}

static __device__ __forceinline__ h2 pack2(float x, float y) {
  h2 r; r[0] = (_Float16)x; r[1] = (_Float16)y; return r;
}

// K1 (MFMA, fused round-0): u_hat[i][b][cell] f16 = sum_l x[b][i][l]*W[i][cell][l]
// via v_mfma_f32_32x32x16_f16 (M=32 b, N=32 cells, K=16 l — exact fit, 1 mfma
// per tile). Slot-pairing-invariant packing (R8-validated): A slot (j,h=lane>>5)
// holds x[m=lane&31][l=j+8h]; B slot (j,h) holds W[cell0+(lane&31)][l=j+8h] —
// correct under any HW slot->k bijection since A and B use the same map.
// C/D (m101): col = lane&31, row = (reg&3)+8*(reg>>2)+4*(lane>>5).
// Layout [i][b][cell]: all stores for one i land in a 128KB window (R8's
// [b][i][cell] scattered 2B stores across 8MB-strided rows -> 362us).
// Round-0 partial: pacc += D (accumulator file), written once -> k_round0 pass
// eliminated. grid (NPC, 16) x 256 thr; wave owns 32-cell column x 8 i's.
__global__ __launch_bounds__(256) void k_conv(const float* __restrict__ x,
                                              const float* __restrict__ W,
                                              __half* __restrict__ uhat,
                                              __half* __restrict__ part) {
  const int ich = blockIdx.x, cg = blockIdx.y, t = threadIdx.x;
  const int wv = t >> 6, lane = t & 63;
  const int n = lane & 31, h = lane >> 5;
  const int i0 = ich * ICH;
  const int cell = cg * 128 + wv * 32 + n;

  // A fragments: x[b=n][i0+ii][l = 8h..8h+7], f32 -> f16.
  f16x8 A[ICH];
  #pragma unroll
  for (int ii = 0; ii < ICH; ++ii) {
    const float* xp = &x[((size_t)n * NI + (i0 + ii)) * NL + 8 * h];
    const f32x4 x0 = *(const f32x4*)xp;
    const f32x4 x1 = *(const f32x4*)(xp + 4);
    f16x8 a;
    a[0] = (f16)x0[0]; a[1] = (f16)x0[1]; a[2] = (f16)x0[2]; a[3] = (f16)x0[3];
    a[4] = (f16)x1[0]; a[5] = (f16)x1[1]; a[6] = (f16)x1[2]; a[7] = (f16)x1[3];
    A[ii] = a;
  }

  f32x16 pacc = {};
  for (int ii = 0; ii < ICH; ++ii) {
    const float* Wp = &W[((size_t)(i0 + ii) * KD + cell) * NL + 8 * h];
    const f32x4 w0 = *(const f32x4*)Wp;
    const f32x4 w1 = *(const f32x4*)(Wp + 4);
    f16x8 Bf;
    Bf[0] = (f16)w0[0]; Bf[1] = (f16)w0[1]; Bf[2] = (f16)w0[2]; Bf[3] = (f16)w0[3];
    Bf[4] = (f16)w1[0]; Bf[5] = (f16)w1[1]; Bf[6] = (f16)w1[2]; Bf[7] = (f16)w1[3];
    const f32x16 z = {};
    const f32x16 D = __builtin_amdgcn_mfma_f32_32x32x16_f16(A[ii], Bf, z, 0, 0, 0);
    __half* up = uhat + (size_t)(i0 + ii) * BB * KD + cell;
    #pragma unroll
    for (int j = 0; j < 16; ++j) {
      const int row = (j & 3) + 8 * (j >> 2) + 4 * h;   // b
      up[(size_t)row * KD] = (__half)D[j];
    }
    pacc = pacc + D;
  }
  #pragma unroll
  for (int j = 0; j < 16; ++j) {
    const int row = (j & 3) + 8 * (j >> 2) + 4 * h;     // b
    part[((size_t)row * NPC + ich) * KD + cell] = (__half)(pacc[j] * (1.f / 64.f));
  }
}

// Routing round, wave-per-i with 2-way i-pairing, no barriers in main loop.
// lane = k; lane holds v[k][:] f16 and sacc[32] f32. u layout [i][b][cell]:
// per (i,b) the wave reads 4KB contiguous. End-of-kernel LDS combine.
__global__ __launch_bounds__(256) void k_route(const __half* __restrict__ uhat,
                                               const float* __restrict__ vin,
                                               __half* __restrict__ part) {
  const int ch = blockIdx.x, b = blockIdx.y, t = threadIdx.x;
  const int wv = t >> 6, lane = t & 63;

  h2 vh[16];
  #pragma unroll
  for (int q = 0; q < 8; ++q) {
    const f32x4 v = *(const f32x4*)&vin[(size_t)b * KD + lane * ND + 4 * q];
    vh[2 * q]     = pack2(v[0], v[1]);
    vh[2 * q + 1] = pack2(v[2], v[3]);
  }

  float sacc[32];
  #pragma unroll
  for (int d = 0; d < 32; ++d) sacc[d] = 0.f;

  const __half* ub = uhat + (size_t)b * KD + lane * ND;   // + i*BB*KD per i
  const int i00 = ch * 64 + wv;
  U4H8 curA[4], curB[4];
  #pragma unroll
  for (int q = 0; q < 4; ++q) {
    curA[q].u4 = *(const uint4*)(ub + (size_t)i00 * BB * KD + 8 * q);
    curB[q].u4 = *(const uint4*)(ub + (size_t)(i00 + 4) * BB * KD + 8 * q);
  }

  for (int p = 0; p < 8; ++p) {
    U4H8 nxtA[4], nxtB[4];
    if (p + 1 < 8) {
      const size_t oA = (size_t)(i00 + 8 * (p + 1)) * BB * KD;
      #pragma unroll
      for (int q = 0; q < 4; ++q) {
        nxtA[q].u4 = *(const uint4*)(ub + oA + 8 * q);
        nxtB[q].u4 = *(const uint4*)(ub + oA + (size_t)4 * BB * KD + 8 * q);
      }
    }
    float agA = 0.f, agB = 0.f;
    #pragma unroll
    for (int q = 0; q < 4; ++q)
      #pragma unroll
      for (int j = 0; j < 4; ++j) {
        agA = dot2f(curA[q].h[j], vh[4 * q + j], agA);
        agB = dot2f(curB[q].h[j], vh[4 * q + j], agB);
      }
    const float eA = __expf(agA);   // logits bounded; no max-subtract needed
    const float eB = __expf(agB);
    float sA = eA, sB = eB;
    sA += __shfl_xor(sA, 1);  sB += __shfl_xor(sB, 1);
    sA += __shfl_xor(sA, 2);  sB += __shfl_xor(sB, 2);
    sA += __shfl_xor(sA, 4);  sB += __shfl_xor(sB, 4);
    sA += __shfl_xor(sA, 8);  sB += __shfl_xor(sB, 8);
    sA += __shfl_xor(sA, 16); sB += __shfl_xor(sB, 16);
    sA += __shfl_xor(sA, 32); sB += __shfl_xor(sB, 32);
    const float cA = eA * fastrcp(sA);
    const float cB = eB * fastrcp(sB);
    #pragma unroll
    for (int q = 0; q < 4; ++q)
      #pragma unroll
      for (int j = 0; j < 4; ++j) {
        sacc[8 * q + 2 * j]     += cA * (float)curA[q].h[j][0]
                                 + cB * (float)curB[q].h[j][0];
        sacc[8 * q + 2 * j + 1] += cA * (float)curA[q].h[j][1]
                                 + cB * (float)curB[q].h[j][1];
      }
    #pragma unroll
    for (int q = 0; q < 4; ++q) { curA[q] = nxtA[q]; curB[q] = nxtB[q]; }
  }

  // Cross-wave combine: red[wv][d][lane] (conflict-free writes), one barrier.
  __shared__ float red[4][ND][64];   // 32 KB
  #pragma unroll
  for (int d = 0; d < ND; ++d) red[wv][d][lane] = sacc[d];
  __syncthreads();
  const int k = t >> 2, d0 = (t & 3) * 8;
  float s[8];
  #pragma unroll
  for (int j = 0; j < 8; ++j)
    s[j] = red[0][d0 + j][k] + red[1][d0 + j][k] +
           red[2][d0 + j][k] + red[3][d0 + j][k];
  U4H8 o;
  #pragma unroll
  for (int j = 0; j < 4; ++j)
    o.h[j] = pack2(s[2 * j], s[2 * j + 1]);
  *(uint4*)&part[((size_t)b * NRC + ch) * KD + 8 * t] = o.u4;
}

// Reduce partials over nch chunks, squash over d=32; optional vprev add
// (round-1 output becomes v0+v1 for the linear-agreement trick).
__global__ __launch_bounds__(256) void k_reduce(const __half* __restrict__ part,
                                                int nch,
                                                const float* __restrict__ vprev,
                                                float* __restrict__ vout) {
  const int g = blockIdx.x, b = blockIdx.y, t = threadIdx.x;
  const int p = g * 256 + t;            // h2-pair index: cells 2p, 2p+1
  const h2* pp = (const h2*)part;
  const size_t base = (size_t)b * nch * (KD / 2) + p;
  float s0 = 0.f, s1 = 0.f;
  for (int ch = 0; ch < nch; ++ch) {
    const h2 v = pp[base + (size_t)ch * (KD / 2)];
    s0 += (float)v[0]; s1 += (float)v[1];
  }
  float sq = s0 * s0 + s1 * s1;
  sq += __shfl_xor(sq, 1); sq += __shfl_xor(sq, 2);
  sq += __shfl_xor(sq, 4); sq += __shfl_xor(sq, 8);
  sq += EPSF;
  const float sc = sqrtf(sq) / (1.f + sq);
  float r0 = s0 * sc, r1 = s1 * sc;
  if (vprev != nullptr) {
    r0 += vprev[(size_t)b * KD + 2 * p];
    r1 += vprev[(size_t)b * KD + 2 * p + 1];
  }
  *(float2*)&vout[(size_t)b * KD + 2 * p] = make_float2(r0, r1);
}

extern "C" void kernel_launch(void* const* d_in, const int* in_sizes, int n_in,
                              void* d_out, int out_size, void* d_ws, size_t ws_size,
                              hipStream_t stream) {
  const float* x = (const float*)d_in[0];   // [32, 2048, 16]
  const float* W = (const float*)d_in[1];   // [2048, 64, 32, 16]
  float* out = (float*)d_out;               // [32, 64, 32]
  char* ws = (char*)d_ws;
  __half* uhat  = (__half*)ws;                                    // 268435456 B
  __half* part0 = (__half*)(ws + 268435456ull);                   // 33554432 B
  __half* partR = (__half*)(ws + 268435456ull + 33554432ull);     // 4194304 B
  float*  vA    = (float*)(ws + 268435456ull + 33554432ull + 4194304ull);
  float*  vB    = vA + (size_t)BB * KD;

  k_conv<<<dim3(NPC, 16), 256, 0, stream>>>(x, W, uhat, part0);
  k_reduce<<<dim3(4, BB), 256, 0, stream>>>(part0, NPC, nullptr, vA);  // v0
  k_route<<<dim3(NRC, BB), 256, 0, stream>>>(uhat, vA, partR);         // u.v0
  k_reduce<<<dim3(4, BB), 256, 0, stream>>>(partR, NRC, vA, vB);       // v0+v1
  k_route<<<dim3(NRC, BB), 256, 0, stream>>>(uhat, vB, partR);         // u.(v0+v1)
  k_reduce<<<dim3(4, BB), 256, 0, stream>>>(partR, NRC, nullptr, out); // v2
}

// Round 16
// 657.286 us; speedup vs baseline: 1.0066x; 1.0066x over previous
//
#include <hip/hip_runtime.h>
#include <hip/hip_fp16.h>

#define BB 32
#define NI 2048
#define NK 64
#define ND 32
#define KD 2048       // caps_n * caps_dim
#define NL 16
#define ICH 8         // i's per conv block
#define NPC (NI/ICH)  // 256 conv i-chunks (round-0 partial count)
#define NRC 32        // route chunks (64 i each)
#define EPSF 1e-7f

typedef _Float16 f16;
typedef _Float16 h2 __attribute__((ext_vector_type(2)));
typedef __attribute__((ext_vector_type(4))) float f32x4;
typedef __attribute__((ext_vector_type(8))) _Float16 f16x8;
typedef __attribute__((ext_vector_type(16))) float f32x16;
union U4H8 { uint4 u4; h2 h[4]; };

static __device__ __forceinline__ float dot2f(h2 a, h2 b, float c) {
#if __has_builtin(__builtin_amdgcn_fdot2)
  return __builtin_amdgcn_fdot2(a, b, c, false);
#else
  return c + (float)a[0] * (float)b[0] + (float)a[1] * (float)b[1];
#endif
}

static __device__ __forceinline__ float fastrcp(float s) {
#if __has_builtin(__builtin_amdgcn_rcpf)
  return __builtin_amdgcn_rcpf(s);
#else
  return 1.0f / s;
#endif
}

static __device__ __forceinline__ h2 pack2(float x, float y) {
  h2 r; r[0] = (_Float16)x; r[1] = (_Float16)y; return r;
}

// K1 (MFMA + LDS store-repack, fused round-0): u_hat[b][i][cell] f16.
// v_mfma_f32_32x32x16_f16 (M=32 b, N=32 cells, K=16 l, exact fit). Packing +
// C/D map validated on HW by R15 (passed): A slot (j,h) = x[lane&31][j+8h],
// B slot (j,h) = W[cell][j+8h]; D: col=lane&31, row=(j&3)+8*(j>>2)+4h.
// R15's 459us came from 16 scattered 2B global stores per lane per i; here the
// fragment goes to an 8KB LDS tile (b16 writes ~2-way conflict), then each
// thread reads 32B row-contiguous and stores 32B wide -> [b][i][cell] layout
// (the one k_route is proven fast on). Round-0 partial fused in pacc (R15:
// no spill) -> k_round0 pass eliminated.
// grid (NPC, 16) x 256 thr; wave owns 32-cell column x 8 i's.
__global__ __launch_bounds__(256) void k_conv(const float* __restrict__ x,
                                              const float* __restrict__ W,
                                              __half* __restrict__ uhat,
                                              __half* __restrict__ part) {
  const int ich = blockIdx.x, cg = blockIdx.y, t = threadIdx.x;
  const int wv = t >> 6, lane = t & 63;
  const int n = lane & 31, h = lane >> 5;
  const int i0 = ich * ICH;
  const int cell = cg * 128 + wv * 32 + n;
  __shared__ __half lds[4][32][32];   // [wave][row=b][col=cell-in-tile] 8 KB

  // store-phase indices: thread t covers b=sb, cells gcell..gcell+15
  const int sb = t >> 3, seg = t & 7;
  const int swv = seg >> 1, colp = (seg & 1) * 16;
  const int gcell = cg * 128 + seg * 16;

  // A fragments: x[b=n][i0+ii][l = 8h..8h+7], f32 -> f16.
  f16x8 A[ICH];
  #pragma unroll
  for (int ii = 0; ii < ICH; ++ii) {
    const float* xp = &x[((size_t)n * NI + (i0 + ii)) * NL + 8 * h];
    const f32x4 x0 = *(const f32x4*)xp;
    const f32x4 x1 = *(const f32x4*)(xp + 4);
    f16x8 a;
    a[0] = (f16)x0[0]; a[1] = (f16)x0[1]; a[2] = (f16)x0[2]; a[3] = (f16)x0[3];
    a[4] = (f16)x1[0]; a[5] = (f16)x1[1]; a[6] = (f16)x1[2]; a[7] = (f16)x1[3];
    A[ii] = a;
  }

  f32x16 pacc = {};
  for (int ii = 0; ii < ICH; ++ii) {
    const float* Wp = &W[((size_t)(i0 + ii) * KD + cell) * NL + 8 * h];
    const f32x4 w0 = *(const f32x4*)Wp;
    const f32x4 w1 = *(const f32x4*)(Wp + 4);
    f16x8 Bf;
    Bf[0] = (f16)w0[0]; Bf[1] = (f16)w0[1]; Bf[2] = (f16)w0[2]; Bf[3] = (f16)w0[3];
    Bf[4] = (f16)w1[0]; Bf[5] = (f16)w1[1]; Bf[6] = (f16)w1[2]; Bf[7] = (f16)w1[3];
    const f32x16 z = {};
    const f32x16 D = __builtin_amdgcn_mfma_f32_32x32x16_f16(A[ii], Bf, z, 0, 0, 0);
    pacc = pacc + D;
    #pragma unroll
    for (int j = 0; j < 16; ++j)
      lds[wv][(j & 3) + 8 * (j >> 2) + 4 * h][n] = (__half)D[j];
    __syncthreads();
    const uint4 lo = *(const uint4*)&lds[swv][sb][colp];
    const uint4 hi = *(const uint4*)&lds[swv][sb][colp + 8];
    __half* up = uhat + ((size_t)sb * NI + (i0 + ii)) * KD + gcell;
    *(uint4*)up = lo;
    *(uint4*)(up + 8) = hi;
    __syncthreads();
  }
  // fused round-0 partial (c = 1/64 uniform), same repack path
  #pragma unroll
  for (int j = 0; j < 16; ++j)
    lds[wv][(j & 3) + 8 * (j >> 2) + 4 * h][n] = (__half)(pacc[j] * (1.f / 64.f));
  __syncthreads();
  {
    const uint4 lo = *(const uint4*)&lds[swv][sb][colp];
    const uint4 hi = *(const uint4*)&lds[swv][sb][colp + 8];
    __half* pp = part + ((size_t)sb * NPC + ich) * KD + gcell;
    *(uint4*)pp = lo;
    *(uint4*)(pp + 8) = hi;
  }
}

// Routing round (R9-proven, [b][i][cell] layout), wave-per-i with 2-way
// i-pairing, no barriers in the main loop. lane = k; lane holds v[k][:] f16
// and sacc[32] f32. End-of-kernel LDS combine -> one partial per block.
__global__ __launch_bounds__(256) void k_route(const __half* __restrict__ uhat,
                                               const float* __restrict__ vin,
                                               __half* __restrict__ part) {
  const int ch = blockIdx.x, b = blockIdx.y, t = threadIdx.x;
  const int wv = t >> 6, lane = t & 63;

  h2 vh[16];
  #pragma unroll
  for (int q = 0; q < 8; ++q) {
    const f32x4 v = *(const f32x4*)&vin[(size_t)b * KD + lane * ND + 4 * q];
    vh[2 * q]     = pack2(v[0], v[1]);
    vh[2 * q + 1] = pack2(v[2], v[3]);
  }

  float sacc[32];
  #pragma unroll
  for (int d = 0; d < 32; ++d) sacc[d] = 0.f;

  const __half* ub = uhat + (size_t)b * NI * KD + lane * ND;
  const int i00 = ch * 64 + wv;
  U4H8 curA[4], curB[4];
  #pragma unroll
  for (int q = 0; q < 4; ++q) {
    curA[q].u4 = *(const uint4*)(ub + (size_t)i00 * KD + 8 * q);
    curB[q].u4 = *(const uint4*)(ub + (size_t)(i00 + 4) * KD + 8 * q);
  }

  for (int p = 0; p < 8; ++p) {
    U4H8 nxtA[4], nxtB[4];
    if (p + 1 < 8) {
      const size_t oA = (size_t)(i00 + 8 * (p + 1)) * KD;
      #pragma unroll
      for (int q = 0; q < 4; ++q) {
        nxtA[q].u4 = *(const uint4*)(ub + oA + 8 * q);
        nxtB[q].u4 = *(const uint4*)(ub + oA + 4 * KD + 8 * q);
      }
    }
    float agA = 0.f, agB = 0.f;
    #pragma unroll
    for (int q = 0; q < 4; ++q)
      #pragma unroll
      for (int j = 0; j < 4; ++j) {
        agA = dot2f(curA[q].h[j], vh[4 * q + j], agA);
        agB = dot2f(curB[q].h[j], vh[4 * q + j], agB);
      }
    const float eA = __expf(agA);   // logits bounded; no max-subtract needed
    const float eB = __expf(agB);
    float sA = eA, sB = eB;
    sA += __shfl_xor(sA, 1);  sB += __shfl_xor(sB, 1);
    sA += __shfl_xor(sA, 2);  sB += __shfl_xor(sB, 2);
    sA += __shfl_xor(sA, 4);  sB += __shfl_xor(sB, 4);
    sA += __shfl_xor(sA, 8);  sB += __shfl_xor(sB, 8);
    sA += __shfl_xor(sA, 16); sB += __shfl_xor(sB, 16);
    sA += __shfl_xor(sA, 32); sB += __shfl_xor(sB, 32);
    const float cA = eA * fastrcp(sA);
    const float cB = eB * fastrcp(sB);
    #pragma unroll
    for (int q = 0; q < 4; ++q)
      #pragma unroll
      for (int j = 0; j < 4; ++j) {
        sacc[8 * q + 2 * j]     += cA * (float)curA[q].h[j][0]
                                 + cB * (float)curB[q].h[j][0];
        sacc[8 * q + 2 * j + 1] += cA * (float)curA[q].h[j][1]
                                 + cB * (float)curB[q].h[j][1];
      }
    #pragma unroll
    for (int q = 0; q < 4; ++q) { curA[q] = nxtA[q]; curB[q] = nxtB[q]; }
  }

  // Cross-wave combine: red[wv][d][lane] (conflict-free writes), one barrier.
  __shared__ float red[4][ND][64];   // 32 KB
  #pragma unroll
  for (int d = 0; d < ND; ++d) red[wv][d][lane] = sacc[d];
  __syncthreads();
  const int k = t >> 2, d0 = (t & 3) * 8;
  float s[8];
  #pragma unroll
  for (int j = 0; j < 8; ++j)
    s[j] = red[0][d0 + j][k] + red[1][d0 + j][k] +
           red[2][d0 + j][k] + red[3][d0 + j][k];
  U4H8 o;
  #pragma unroll
  for (int j = 0; j < 4; ++j)
    o.h[j] = pack2(s[2 * j], s[2 * j + 1]);
  *(uint4*)&part[((size_t)b * NRC + ch) * KD + 8 * t] = o.u4;
}

// Reduce partials over nch chunks, squash over d=32; optional vprev add
// (round-1 output becomes v0+v1 for the linear-agreement trick).
__global__ __launch_bounds__(256) void k_reduce(const __half* __restrict__ part,
                                                int nch,
                                                const float* __restrict__ vprev,
                                                float* __restrict__ vout) {
  const int g = blockIdx.x, b = blockIdx.y, t = threadIdx.x;
  const int p = g * 256 + t;            // h2-pair index: cells 2p, 2p+1
  const h2* pp = (const h2*)part;
  const size_t base = (size_t)b * nch * (KD / 2) + p;
  float s0 = 0.f, s1 = 0.f;
  for (int ch = 0; ch < nch; ++ch) {
    const h2 v = pp[base + (size_t)ch * (KD / 2)];
    s0 += (float)v[0]; s1 += (float)v[1];
  }
  float sq = s0 * s0 + s1 * s1;
  sq += __shfl_xor(sq, 1); sq += __shfl_xor(sq, 2);
  sq += __shfl_xor(sq, 4); sq += __shfl_xor(sq, 8);
  sq += EPSF;
  const float sc = sqrtf(sq) / (1.f + sq);
  float r0 = s0 * sc, r1 = s1 * sc;
  if (vprev != nullptr) {
    r0 += vprev[(size_t)b * KD + 2 * p];
    r1 += vprev[(size_t)b * KD + 2 * p + 1];
  }
  *(float2*)&vout[(size_t)b * KD + 2 * p] = make_float2(r0, r1);
}

extern "C" void kernel_launch(void* const* d_in, const int* in_sizes, int n_in,
                              void* d_out, int out_size, void* d_ws, size_t ws_size,
                              hipStream_t stream) {
  const float* x = (const float*)d_in[0];   // [32, 2048, 16]
  const float* W = (const float*)d_in[1];   // [2048, 64, 32, 16]
  float* out = (float*)d_out;               // [32, 64, 32]
  char* ws = (char*)d_ws;
  __half* uhat  = (__half*)ws;                                    // 268435456 B
  __half* part0 = (__half*)(ws + 268435456ull);                   // 33554432 B
  __half* partR = (__half*)(ws + 268435456ull + 33554432ull);     // 4194304 B
  float*  vA    = (float*)(ws + 268435456ull + 33554432ull + 4194304ull);
  float*  vB    = vA + (size_t)BB * KD;

  k_conv<<<dim3(NPC, 16), 256, 0, stream>>>(x, W, uhat, part0);
  k_reduce<<<dim3(4, BB), 256, 0, stream>>>(part0, NPC, nullptr, vA);  // v0
  k_route<<<dim3(NRC, BB), 256, 0, stream>>>(uhat, vA, partR);         // u.v0
  k_reduce<<<dim3(4, BB), 256, 0, stream>>>(partR, NRC, vA, vB);       // v0+v1
  k_route<<<dim3(NRC, BB), 256, 0, stream>>>(uhat, vB, partR);         // u.(v0+v1)
  k_reduce<<<dim3(4, BB), 256, 0, stream>>>(partR, NRC, nullptr, out); // v2
}

// Round 17
// 426.861 us; speedup vs baseline: 1.5500x; 1.5398x over previous
//
#include <hip/hip_runtime.h>
#include <hip/hip_fp16.h>

#define BB 32
#define NI 2048
#define NK 64
#define ND 32
#define KD 2048       // caps_n * caps_dim
#define NL 16
#define ITC 16        // i's per conv block
#define NPC (NI/ITC)  // 128 conv i-chunks (round-0 partial count)
#define CCH 64        // cells per conv block
#define NCG (KD/CCH)  // 32
#define NRC 32        // route chunks (64 i each)
#define EPSF 1e-7f

typedef _Float16 f16;
typedef _Float16 h2 __attribute__((ext_vector_type(2)));
typedef __attribute__((ext_vector_type(4))) float f32x4;
union U4H8 { uint4 u4; h2 h[4]; };
union UH2  { unsigned u; h2 h; };

static __device__ __forceinline__ float dot2f(h2 a, h2 b, float c) {
#if __has_builtin(__builtin_amdgcn_fdot2)
  return __builtin_amdgcn_fdot2(a, b, c, false);
#else
  return c + (float)a[0] * (float)b[0] + (float)a[1] * (float)b[1];
#endif
}

static __device__ __forceinline__ float fastrcp(float s) {
#if __has_builtin(__builtin_amdgcn_rcpf)
  return __builtin_amdgcn_rcpf(s);
#else
  return 1.0f / s;
#endif
}

static __device__ __forceinline__ h2 pack2(float x, float y) {
  h2 r; r[0] = (_Float16)x; r[1] = (_Float16)y; return r;
}

// K1 (fused conv + round-0): u_hat[b][i][cell] f16 = sum_l W*x.
// 16-round synthesis: (i) W-in-registers across a loop gets rematerialized /
// starved by the allocator (R9/R13/R14); (ii) per-b LDS x-re-reads serialize
// the DS pipe (R9); (iii) per-lane x loads saturate VMEM (R12); (iv) MFMA
// marshalling+barriers cost more than K=16 matmul saves (R8/R15/R16).
// This shape dodges all four: x is the REGISTER operand (LDS-sourced h2,
// loaded once per i, live only within the iteration, broadcast ds_read_b128 =
// conflict-free); W is the STREAMED transient (8 coalesced float4 per i,
// converted and consumed immediately - no long live range to attack).
// Thread = (cell-pair cp, b-quarter bq): 2 cells x 4 b; peak regs ~70.
// Per i: 8 ds_read_b128 + 8 float4 + 64 v_dot2 + 4 u32 stores.
// grid (NPC, NCG) x 256 thr. Round-0 partial in sacc[8] -> k_round0 gone.
__global__ __launch_bounds__(256) void k_conv(const float* __restrict__ x,
                                              const float* __restrict__ W,
                                              __half* __restrict__ uhat,
                                              __half* __restrict__ part) {
  const int ich = blockIdx.x, cg = blockIdx.y, t = threadIdx.x;
  const int cp = t & 31, bq = t >> 5;       // cp 0..31, bq 0..7
  const int i0 = ich * ITC;
  const int c0 = cg * CCH + 2 * cp;
  __shared__ uint4 xs[ITC][33][2];          // [i][b(+pad)][half], 32B per (i,b)

  // Stage x -> LDS f16: rows r = t, t+256; i = r&15, b = r>>4 (consecutive
  // threads read consecutive i => 1KB-contiguous global bursts per b).
  #pragma unroll
  for (int q = 0; q < 2; ++q) {
    const int r = t + q * 256;
    const int bi = r >> 4, il = r & 15;
    const float* xp = &x[((size_t)bi * NI + i0 + il) * NL];
    const f32x4 a = *(const f32x4*)xp;
    const f32x4 b2 = *(const f32x4*)(xp + 4);
    const f32x4 c = *(const f32x4*)(xp + 8);
    const f32x4 d = *(const f32x4*)(xp + 12);
    U4H8 lo, hi;
    lo.h[0] = pack2(a[0], a[1]);  lo.h[1] = pack2(a[2], a[3]);
    lo.h[2] = pack2(b2[0], b2[1]); lo.h[3] = pack2(b2[2], b2[3]);
    hi.h[0] = pack2(c[0], c[1]);  hi.h[1] = pack2(c[2], c[3]);
    hi.h[2] = pack2(d[0], d[1]);  hi.h[3] = pack2(d[2], d[3]);
    xs[il][bi][0] = lo.u4;
    xs[il][bi][1] = hi.u4;
  }
  __syncthreads();

  float sacc[8];                            // [r 0..3][cellA/cellB]
  #pragma unroll
  for (int j = 0; j < 8; ++j) sacc[j] = 0.f;

  for (int ii = 0; ii < ITC; ++ii) {
    const int i = i0 + ii;
    U4H8 xr[4][2];                          // 4 b-rows x 16 f16 (broadcast reads)
    #pragma unroll
    for (int r = 0; r < 4; ++r) {
      xr[r][0].u4 = xs[ii][bq * 4 + r][0];
      xr[r][1].u4 = xs[ii][bq * 4 + r][1];
    }
    const float* Wp = W + ((size_t)i * KD + c0) * NL;
    h2 wA[8], wB[8];
    #pragma unroll
    for (int q = 0; q < 4; ++q) {
      const f32x4 f = *(const f32x4*)(Wp + 4 * q);
      wA[2 * q] = pack2(f[0], f[1]); wA[2 * q + 1] = pack2(f[2], f[3]);
    }
    #pragma unroll
    for (int q = 0; q < 4; ++q) {
      const f32x4 f = *(const f32x4*)(Wp + NL + 4 * q);
      wB[2 * q] = pack2(f[0], f[1]); wB[2 * q + 1] = pack2(f[2], f[3]);
    }
    #pragma unroll
    for (int r = 0; r < 4; ++r) {
      float uA = 0.f, uB = 0.f;
      #pragma unroll
      for (int j = 0; j < 4; ++j) {
        uA = dot2f(wA[j],     xr[r][0].h[j], uA);
        uA = dot2f(wA[4 + j], xr[r][1].h[j], uA);
        uB = dot2f(wB[j],     xr[r][0].h[j], uB);
        uB = dot2f(wB[4 + j], xr[r][1].h[j], uB);
      }
      const int b = bq * 4 + r;
      UH2 o; o.h = pack2(uA, uB);
      *(unsigned*)&uhat[((size_t)b * NI + i) * KD + c0] = o.u;
      sacc[2 * r] += uA; sacc[2 * r + 1] += uB;
    }
  }
  #pragma unroll
  for (int r = 0; r < 4; ++r) {
    const int b = bq * 4 + r;
    UH2 o;
    o.h = pack2(sacc[2 * r] * (1.f / 64.f), sacc[2 * r + 1] * (1.f / 64.f));
    *(unsigned*)&part[((size_t)b * NPC + ich) * KD + c0] = o.u;
  }
}

// Routing round (R9-proven), wave-per-i with 2-way i-pairing, no barriers in
// the main loop. lane = k; lane holds v[k][:] f16 and sacc[32] f32.
// End-of-kernel LDS combine -> one partial per block (nch = NRC).
__global__ __launch_bounds__(256) void k_route(const __half* __restrict__ uhat,
                                               const float* __restrict__ vin,
                                               __half* __restrict__ part) {
  const int ch = blockIdx.x, b = blockIdx.y, t = threadIdx.x;
  const int wv = t >> 6, lane = t & 63;

  h2 vh[16];
  #pragma unroll
  for (int q = 0; q < 8; ++q) {
    const f32x4 v = *(const f32x4*)&vin[(size_t)b * KD + lane * ND + 4 * q];
    vh[2 * q]     = pack2(v[0], v[1]);
    vh[2 * q + 1] = pack2(v[2], v[3]);
  }

  float sacc[32];
  #pragma unroll
  for (int d = 0; d < 32; ++d) sacc[d] = 0.f;

  const __half* ub = uhat + (size_t)b * NI * KD + lane * ND;
  const int i00 = ch * 64 + wv;
  U4H8 curA[4], curB[4];
  #pragma unroll
  for (int q = 0; q < 4; ++q) {
    curA[q].u4 = *(const uint4*)(ub + (size_t)i00 * KD + 8 * q);
    curB[q].u4 = *(const uint4*)(ub + (size_t)(i00 + 4) * KD + 8 * q);
  }

  for (int p = 0; p < 8; ++p) {
    U4H8 nxtA[4], nxtB[4];
    if (p + 1 < 8) {
      const size_t oA = (size_t)(i00 + 8 * (p + 1)) * KD;
      #pragma unroll
      for (int q = 0; q < 4; ++q) {
        nxtA[q].u4 = *(const uint4*)(ub + oA + 8 * q);
        nxtB[q].u4 = *(const uint4*)(ub + oA + 4 * KD + 8 * q);
      }
    }
    float agA = 0.f, agB = 0.f;
    #pragma unroll
    for (int q = 0; q < 4; ++q)
      #pragma unroll
      for (int j = 0; j < 4; ++j) {
        agA = dot2f(curA[q].h[j], vh[4 * q + j], agA);
        agB = dot2f(curB[q].h[j], vh[4 * q + j], agB);
      }
    const float eA = __expf(agA);   // logits bounded; no max-subtract needed
    const float eB = __expf(agB);
    float sA = eA, sB = eB;
    sA += __shfl_xor(sA, 1);  sB += __shfl_xor(sB, 1);
    sA += __shfl_xor(sA, 2);  sB += __shfl_xor(sB, 2);
    sA += __shfl_xor(sA, 4);  sB += __shfl_xor(sB, 4);
    sA += __shfl_xor(sA, 8);  sB += __shfl_xor(sB, 8);
    sA += __shfl_xor(sA, 16); sB += __shfl_xor(sB, 16);
    sA += __shfl_xor(sA, 32); sB += __shfl_xor(sB, 32);
    const float cA = eA * fastrcp(sA);
    const float cB = eB * fastrcp(sB);
    #pragma unroll
    for (int q = 0; q < 4; ++q)
      #pragma unroll
      for (int j = 0; j < 4; ++j) {
        sacc[8 * q + 2 * j]     += cA * (float)curA[q].h[j][0]
                                 + cB * (float)curB[q].h[j][0];
        sacc[8 * q + 2 * j + 1] += cA * (float)curA[q].h[j][1]
                                 + cB * (float)curB[q].h[j][1];
      }
    #pragma unroll
    for (int q = 0; q < 4; ++q) { curA[q] = nxtA[q]; curB[q] = nxtB[q]; }
  }

  // Cross-wave combine: red[wv][d][lane] (conflict-free writes), one barrier.
  __shared__ float red[4][ND][64];   // 32 KB
  #pragma unroll
  for (int d = 0; d < ND; ++d) red[wv][d][lane] = sacc[d];
  __syncthreads();
  const int k = t >> 2, d0 = (t & 3) * 8;
  float s[8];
  #pragma unroll
  for (int j = 0; j < 8; ++j)
    s[j] = red[0][d0 + j][k] + red[1][d0 + j][k] +
           red[2][d0 + j][k] + red[3][d0 + j][k];
  U4H8 o;
  #pragma unroll
  for (int j = 0; j < 4; ++j)
    o.h[j] = pack2(s[2 * j], s[2 * j + 1]);
  *(uint4*)&part[((size_t)b * NRC + ch) * KD + 8 * t] = o.u4;
}

// Reduce partials over nch chunks, squash over d=32; optional vprev add
// (round-1 output becomes v0+v1 for the linear-agreement trick).
__global__ __launch_bounds__(256) void k_reduce(const __half* __restrict__ part,
                                                int nch,
                                                const float* __restrict__ vprev,
                                                float* __restrict__ vout) {
  const int g = blockIdx.x, b = blockIdx.y, t = threadIdx.x;
  const int p = g * 256 + t;            // h2-pair index: cells 2p, 2p+1
  const h2* pp = (const h2*)part;
  const size_t base = (size_t)b * nch * (KD / 2) + p;
  float s0 = 0.f, s1 = 0.f;
  for (int ch = 0; ch < nch; ++ch) {
    const h2 v = pp[base + (size_t)ch * (KD / 2)];
    s0 += (float)v[0]; s1 += (float)v[1];
  }
  float sq = s0 * s0 + s1 * s1;
  sq += __shfl_xor(sq, 1); sq += __shfl_xor(sq, 2);
  sq += __shfl_xor(sq, 4); sq += __shfl_xor(sq, 8);
  sq += EPSF;
  const float sc = sqrtf(sq) / (1.f + sq);
  float r0 = s0 * sc, r1 = s1 * sc;
  if (vprev != nullptr) {
    r0 += vprev[(size_t)b * KD + 2 * p];
    r1 += vprev[(size_t)b * KD + 2 * p + 1];
  }
  *(float2*)&vout[(size_t)b * KD + 2 * p] = make_float2(r0, r1);
}

extern "C" void kernel_launch(void* const* d_in, const int* in_sizes, int n_in,
                              void* d_out, int out_size, void* d_ws, size_t ws_size,
                              hipStream_t stream) {
  const float* x = (const float*)d_in[0];   // [32, 2048, 16]
  const float* W = (const float*)d_in[1];   // [2048, 64, 32, 16]
  float* out = (float*)d_out;               // [32, 64, 32]
  char* ws = (char*)d_ws;
  __half* uhat  = (__half*)ws;                                    // 268435456 B
  __half* part0 = (__half*)(ws + 268435456ull);                   // 16777216 B
  __half* partR = (__half*)(ws + 268435456ull + 16777216ull);     // 4194304 B
  float*  vA    = (float*)(ws + 268435456ull + 16777216ull + 4194304ull);
  float*  vB    = vA + (size_t)BB * KD;

  k_conv<<<dim3(NPC, NCG), 256, 0, stream>>>(x, W, uhat, part0);
  k_reduce<<<dim3(4, BB), 256, 0, stream>>>(part0, NPC, nullptr, vA);  // v0
  k_route<<<dim3(NRC, BB), 256, 0, stream>>>(uhat, vA, partR);         // u.v0
  k_reduce<<<dim3(4, BB), 256, 0, stream>>>(partR, NRC, vA, vB);       // v0+v1
  k_route<<<dim3(NRC, BB), 256, 0, stream>>>(uhat, vB, partR);         // u.(v0+v1)
  k_reduce<<<dim3(4, BB), 256, 0, stream>>>(partR, NRC, nullptr, out); // v2
}

// Round 18
// 296.706 us; speedup vs baseline: 2.2299x; 1.4387x over previous
//
#include <hip/hip_runtime.h>
#include <hip/hip_fp16.h>

#define BB 32
#define NI 2048
#define NK 64
#define ND 32
#define KD 2048       // caps_n * caps_dim
#define NL 16
#define NCH0 64       // round-0 chunks (32 i each)
#define NRC 32        // route chunks (64 i each)
#define EPSF 1e-7f

typedef _Float16 f16;
typedef _Float16 h2 __attribute__((ext_vector_type(2)));
typedef __attribute__((ext_vector_type(4))) float f32x4;
union U4H8 { uint4 u4; h2 h[4]; };
union UH2  { unsigned u; h2 h; };

static __device__ __forceinline__ float dot2f(h2 a, h2 b, float c) {
#if __has_builtin(__builtin_amdgcn_fdot2)
  return __builtin_amdgcn_fdot2(a, b, c, false);
#else
  return c + (float)a[0] * (float)b[0] + (float)a[1] * (float)b[1];
#endif
}

static __device__ __forceinline__ float fastrcp(float s) {
#if __has_builtin(__builtin_amdgcn_rcpf)
  return __builtin_amdgcn_rcpf(s);
#else
  return 1.0f / s;
#endif
}

static __device__ __forceinline__ h2 pack2(float x, float y) {
  h2 r; r[0] = (_Float16)x; r[1] = (_Float16)y; return r;
}

// K1: u_hat[b][i][cell] f16 = sum_l W[i][cell][l] * x[b][i][l].
// R18: designed for the allocator's observed ~40-VGPR grant (10 conv variants
// all got 28-64 regs; anything larger re-reads operands). Working set: W tile
// as h2 = 16 VGPR (the one change vs R13, whose 32 f32 W regs exceeded its
// 32-reg grant and were re-read from L2 every b), x transient 8, acc 2,
// addr ~6 -> ~32 regs. x LDS-staged as f16 (scalar 2B writes, broadcast
// ds_read_b128 reads, conflict-free). Per b: 2 ds_read_b128 + 16 v_dot2 +
// one packed 4B store. grid (NI, 2) x 512 thr; cells c0 = half*1024 + 2t.
__global__ __launch_bounds__(512) void k_uhat(const float* __restrict__ x,
                                              const float* __restrict__ W,
                                              __half* __restrict__ uhat) {
  const int i = blockIdx.x, half = blockIdx.y;
  const int t = threadIdx.x;
  const int c0 = half * 1024 + 2 * t;
  __shared__ __half xs[BB][NL];   // 1 KB
  xs[t >> 4][t & 15] = (__half)x[((size_t)(t >> 4) * NI + i) * NL + (t & 15)];
  __syncthreads();

  // W tile: 2 cells x 16 l, converted to 16 h2 regs (consumed from 8 float4).
  h2 w[16];
  {
    const float* Wp = W + ((size_t)i * KD + c0) * NL;
    #pragma unroll
    for (int q = 0; q < 4; ++q) {
      const f32x4 f = *(const f32x4*)(Wp + 4 * q);
      w[2 * q] = pack2(f[0], f[1]); w[2 * q + 1] = pack2(f[2], f[3]);
    }
    #pragma unroll
    for (int q = 0; q < 4; ++q) {
      const f32x4 f = *(const f32x4*)(Wp + NL + 4 * q);
      w[8 + 2 * q] = pack2(f[0], f[1]); w[8 + 2 * q + 1] = pack2(f[2], f[3]);
    }
  }

  __half* up = uhat + (size_t)i * KD + c0;
  for (int b = 0; b < BB; ++b) {
    U4H8 x0, x1;
    x0.u4 = *(const uint4*)&xs[b][0];
    x1.u4 = *(const uint4*)&xs[b][8];
    float u0 = 0.f, u1 = 0.f;
    #pragma unroll
    for (int j = 0; j < 4; ++j) {
      u0 = dot2f(w[j],     x0.h[j], u0);
      u0 = dot2f(w[4 + j], x1.h[j], u0);
      u1 = dot2f(w[8 + j],  x0.h[j], u1);
      u1 = dot2f(w[12 + j], x1.h[j], u1);
    }
    UH2 o; o.h = pack2(u0, u1);
    *(unsigned*)(up + (size_t)b * NI * KD) = o.u;
  }
}

// K2: round-0 partials (c = 1/64 uniform): part[b][ch][cell] f16.
// grid (NCH0, BB), 256 thr; thread owns 8 cells via 16B loads.
__global__ __launch_bounds__(256) void k_round0(const __half* __restrict__ uhat,
                                                __half* __restrict__ part) {
  const int ch = blockIdx.x, b = blockIdx.y, t = threadIdx.x;
  float acc[8];
  #pragma unroll
  for (int j = 0; j < 8; ++j) acc[j] = 0.f;
  const __half* up = uhat + ((size_t)b * NI + (size_t)ch * 32) * KD + t * 8;
  for (int il = 0; il < 32; ++il) {
    U4H8 u; u.u4 = *(const uint4*)(up + (size_t)il * KD);
    #pragma unroll
    for (int j = 0; j < 4; ++j) {
      acc[2 * j]     += (float)u.h[j][0];
      acc[2 * j + 1] += (float)u.h[j][1];
    }
  }
  U4H8 o;
  #pragma unroll
  for (int j = 0; j < 4; ++j)
    o.h[j] = pack2(acc[2 * j] * (1.f / 64.f), acc[2 * j + 1] * (1.f / 64.f));
  *(uint4*)&part[((size_t)b * NCH0 + ch) * KD + t * 8] = o.u4;
}

// Routing round (R9-proven), wave-per-i with 2-way i-pairing, no barriers in
// the main loop. lane = k; lane holds v[k][:] f16 and sacc[32] f32.
// End-of-kernel LDS combine -> one partial per block (nch = NRC).
__global__ __launch_bounds__(256) void k_route(const __half* __restrict__ uhat,
                                               const float* __restrict__ vin,
                                               __half* __restrict__ part) {
  const int ch = blockIdx.x, b = blockIdx.y, t = threadIdx.x;
  const int wv = t >> 6, lane = t & 63;

  h2 vh[16];
  #pragma unroll
  for (int q = 0; q < 8; ++q) {
    const f32x4 v = *(const f32x4*)&vin[(size_t)b * KD + lane * ND + 4 * q];
    vh[2 * q]     = pack2(v[0], v[1]);
    vh[2 * q + 1] = pack2(v[2], v[3]);
  }

  float sacc[32];
  #pragma unroll
  for (int d = 0; d < 32; ++d) sacc[d] = 0.f;

  const __half* ub = uhat + (size_t)b * NI * KD + lane * ND;
  const int i00 = ch * 64 + wv;
  U4H8 curA[4], curB[4];
  #pragma unroll
  for (int q = 0; q < 4; ++q) {
    curA[q].u4 = *(const uint4*)(ub + (size_t)i00 * KD + 8 * q);
    curB[q].u4 = *(const uint4*)(ub + (size_t)(i00 + 4) * KD + 8 * q);
  }

  for (int p = 0; p < 8; ++p) {
    U4H8 nxtA[4], nxtB[4];
    if (p + 1 < 8) {
      const size_t oA = (size_t)(i00 + 8 * (p + 1)) * KD;
      #pragma unroll
      for (int q = 0; q < 4; ++q) {
        nxtA[q].u4 = *(const uint4*)(ub + oA + 8 * q);
        nxtB[q].u4 = *(const uint4*)(ub + oA + 4 * KD + 8 * q);
      }
    }
    float agA = 0.f, agB = 0.f;
    #pragma unroll
    for (int q = 0; q < 4; ++q)
      #pragma unroll
      for (int j = 0; j < 4; ++j) {
        agA = dot2f(curA[q].h[j], vh[4 * q + j], agA);
        agB = dot2f(curB[q].h[j], vh[4 * q + j], agB);
      }
    const float eA = __expf(agA);   // logits bounded; no max-subtract needed
    const float eB = __expf(agB);
    float sA = eA, sB = eB;
    sA += __shfl_xor(sA, 1);  sB += __shfl_xor(sB, 1);
    sA += __shfl_xor(sA, 2);  sB += __shfl_xor(sB, 2);
    sA += __shfl_xor(sA, 4);  sB += __shfl_xor(sB, 4);
    sA += __shfl_xor(sA, 8);  sB += __shfl_xor(sB, 8);
    sA += __shfl_xor(sA, 16); sB += __shfl_xor(sB, 16);
    sA += __shfl_xor(sA, 32); sB += __shfl_xor(sB, 32);
    const float cA = eA * fastrcp(sA);
    const float cB = eB * fastrcp(sB);
    #pragma unroll
    for (int q = 0; q < 4; ++q)
      #pragma unroll
      for (int j = 0; j < 4; ++j) {
        sacc[8 * q + 2 * j]     += cA * (float)curA[q].h[j][0]
                                 + cB * (float)curB[q].h[j][0];
        sacc[8 * q + 2 * j + 1] += cA * (float)curA[q].h[j][1]
                                 + cB * (float)curB[q].h[j][1];
      }
    #pragma unroll
    for (int q = 0; q < 4; ++q) { curA[q] = nxtA[q]; curB[q] = nxtB[q]; }
  }

  // Cross-wave combine: red[wv][d][lane] (conflict-free writes), one barrier.
  __shared__ float red[4][ND][64];   // 32 KB
  #pragma unroll
  for (int d = 0; d < ND; ++d) red[wv][d][lane] = sacc[d];
  __syncthreads();
  const int k = t >> 2, d0 = (t & 3) * 8;
  float s[8];
  #pragma unroll
  for (int j = 0; j < 8; ++j)
    s[j] = red[0][d0 + j][k] + red[1][d0 + j][k] +
           red[2][d0 + j][k] + red[3][d0 + j][k];
  U4H8 o;
  #pragma unroll
  for (int j = 0; j < 4; ++j)
    o.h[j] = pack2(s[2 * j], s[2 * j + 1]);
  *(uint4*)&part[((size_t)b * NRC + ch) * KD + 8 * t] = o.u4;
}

// Reduce partials over nch chunks, squash over d=32; optional vprev add
// (round-1 output becomes v0+v1 for the linear-agreement trick).
__global__ __launch_bounds__(256) void k_reduce(const __half* __restrict__ part,
                                                int nch,
                                                const float* __restrict__ vprev,
                                                float* __restrict__ vout) {
  const int g = blockIdx.x, b = blockIdx.y, t = threadIdx.x;
  const int p = g * 256 + t;            // h2-pair index: cells 2p, 2p+1
  const h2* pp = (const h2*)part;
  const size_t base = (size_t)b * nch * (KD / 2) + p;
  float s0 = 0.f, s1 = 0.f;
  for (int ch = 0; ch < nch; ++ch) {
    const h2 v = pp[base + (size_t)ch * (KD / 2)];
    s0 += (float)v[0]; s1 += (float)v[1];
  }
  float sq = s0 * s0 + s1 * s1;
  sq += __shfl_xor(sq, 1); sq += __shfl_xor(sq, 2);
  sq += __shfl_xor(sq, 4); sq += __shfl_xor(sq, 8);
  sq += EPSF;
  const float sc = sqrtf(sq) / (1.f + sq);
  float r0 = s0 * sc, r1 = s1 * sc;
  if (vprev != nullptr) {
    r0 += vprev[(size_t)b * KD + 2 * p];
    r1 += vprev[(size_t)b * KD + 2 * p + 1];
  }
  *(float2*)&vout[(size_t)b * KD + 2 * p] = make_float2(r0, r1);
}

extern "C" void kernel_launch(void* const* d_in, const int* in_sizes, int n_in,
                              void* d_out, int out_size, void* d_ws, size_t ws_size,
                              hipStream_t stream) {
  const float* x = (const float*)d_in[0];   // [32, 2048, 16]
  const float* W = (const float*)d_in[1];   // [2048, 64, 32, 16]
  float* out = (float*)d_out;               // [32, 64, 32]
  char* ws = (char*)d_ws;
  __half* uhat  = (__half*)ws;                                    // 268435456 B
  __half* part0 = (__half*)(ws + 268435456ull);                   // 8388608 B
  __half* partR = (__half*)(ws + 268435456ull + 8388608ull);      // 4194304 B
  float*  vA    = (float*)(ws + 268435456ull + 8388608ull + 4194304ull);
  float*  vB    = vA + (size_t)BB * KD;

  k_uhat<<<dim3(NI, 2), 512, 0, stream>>>(x, W, uhat);
  k_round0<<<dim3(NCH0, BB), 256, 0, stream>>>(uhat, part0);
  k_reduce<<<dim3(4, BB), 256, 0, stream>>>(part0, NCH0, nullptr, vA);  // v0
  k_route<<<dim3(NRC, BB), 256, 0, stream>>>(uhat, vA, partR);          // u.v0
  k_reduce<<<dim3(4, BB), 256, 0, stream>>>(partR, NRC, vA, vB);        // v0+v1
  k_route<<<dim3(NRC, BB), 256, 0, stream>>>(uhat, vB, partR);          // u.(v0+v1)
  k_reduce<<<dim3(4, BB), 256, 0, stream>>>(partR, NRC, nullptr, out);  // v2
}